// Round 2
// baseline (5054.868 us; speedup 1.0000x reference)
//
#include <hip/hip_runtime.h>

// ---------------------------------------------------------------------------
// LSTM layer, T=512 B=64 I=H=1024, bf16 MFMA path.
// d_in: x[T,B,I], h0[B,H], c0[B,H], W_ih[4H,I], W_hh[4H,H], b_ih[4H], b_hh[4H]
// d_out: outputs[T,B,H] ++ hT[B,H] ++ cT[B,H]  (fp32)
//
// Round 5:
//  - h exchange redesigned: self-validating ring of u32 {bf16(h)<<16 | tag}.
//    No producer drain, no flag store, no flag poll -- consumers bypass-load
//    (sc0 sc1) the data directly and validate per-word tags, selectively
//    re-loading stale chunks. Collapses the 4 serial cross-die hops of the
//    flag protocol into one LLC landing latency.
//  - Ring is 8 slots x 64x1024 u32 = 2 MB (tag disambiguates slot reuse;
//    inter-block skew bound is 1 step). Stays LLC-resident.
//  - W_hh moved LDS -> 128 VGPR/wave; LDS now holds double-buffered
//    XOR-swizzled h tile (hbf) for conflict-free ds_read_b128 A-frags.
//    A-feed deduped: each wave stages 4 rows once (was 4x32KB redundant).
//  - 2 barriers/step (was 3). k_xproj unchanged (verified m97 structure).
// ---------------------------------------------------------------------------

typedef __attribute__((ext_vector_type(8))) short bf16x8;
typedef __attribute__((ext_vector_type(4))) short bf16x4;
typedef __attribute__((ext_vector_type(4))) float f32x4;
typedef __attribute__((ext_vector_type(4))) unsigned int u32x4;
typedef unsigned long long u64;

#define T_STEPS 512
#define BATCH   64
#define HID     1024
#define G4      4096
#define BH      (BATCH * HID)
#define NSLOT   8

// ws layout (bytes)
#define OFF_XPT   ((size_t)0)            // bf16 [4096][32768] transposed x-proj (+bias)
#define OFF_RING  ((size_t)268435456)    // u32 [8][64][1024] tagged h ring (2 MB)
#define OFF_WIB   ((size_t)335544320)    // bf16 [4096][1024] W_ih
#define OFF_WHB   ((size_t)343932928)    // bf16 [4096][1024] W_hh
#define OFF_BSUM  ((size_t)352321536)    // f32 [4096] b_ih+b_hh

__device__ __forceinline__ unsigned short f2bf(float f) {
  unsigned int u = __float_as_uint(f);
  u += 0x7FFFu + ((u >> 16) & 1u);
  return (unsigned short)(u >> 16);
}
__device__ __forceinline__ float bf2f(short s) {
  return __uint_as_float(((unsigned int)(unsigned short)s) << 16);
}
__device__ __forceinline__ float sigm(float x) { return 1.0f / (1.0f + __expf(-x)); }
__device__ __forceinline__ float tanh_f(float x) {
  float e = __expf(-2.0f * fabsf(x));
  float r = (1.0f - e) / (1.0f + e);
  return x < 0.0f ? -r : r;
}

// async global->LDS, 16B per lane. LDS dest is wave-uniform base + lane*16.
__device__ __forceinline__ void gl_lds16(const unsigned short* g, unsigned short* l) {
  __builtin_amdgcn_global_load_lds(
      (const __attribute__((address_space(1))) unsigned int*)g,
      (__attribute__((address_space(3))) unsigned int*)l, 16, 0, 0);
}

// LLC-bypass 16B load (sc0 sc1: skip L1+L2, read LLC-fresh). No waitcnt inside:
// caller batches loads, then waitcnt vmcnt(0) + sched_barrier(0) before use.
__device__ __forceinline__ u32x4 llc_load4(const unsigned int* p) {
  u32x4 r;
  asm volatile("global_load_dwordx4 %0, %1, off sc0 sc1"
               : "=&v"(r) : "v"(p));
  return r;
}

// ---------------------------------------------------------------------------
__global__ void k_cast_bf16(const float* __restrict__ src,
                            unsigned short* __restrict__ dst, int n) {
  int i = (blockIdx.x * 256 + threadIdx.x) * 4;
  if (i >= n) return;
  float4 v = *(const float4*)(src + i);
  bf16x4 o;
  o[0] = (short)f2bf(v.x); o[1] = (short)f2bf(v.y);
  o[2] = (short)f2bf(v.z); o[3] = (short)f2bf(v.w);
  *(bf16x4*)(dst + i) = o;
}

__global__ void k_bias(const float* __restrict__ bi, const float* __restrict__ bh,
                       float* __restrict__ bs) {
  int i = blockIdx.x * 256 + threadIdx.x;
  if (i < G4) bs[i] = bi[i] + bh[i];
}

// h0 -> ring slot 0 as tagged u32 (tag 0). Agent-scope stores so the data is
// LLC-visible to k_lstm's bypass loads.
__global__ void k_h0_pack(const float* __restrict__ h0,
                          unsigned int* __restrict__ ring32) {
  int i = blockIdx.x * 256 + threadIdx.x;
  unsigned int pk = ((unsigned int)f2bf(h0[i]) << 16);
  __hip_atomic_store(ring32 + i, pk, __ATOMIC_RELAXED, __HIP_MEMORY_SCOPE_AGENT);
}

// ---------------------------------------------------------------------------
// x-projection GEMM: xpT[n][m] = sum_k xb[m][k]*wib[n][k] + bsum[n]  (bf16 out)
// Verified m97 structure (round 4): 128x128 tile, BK=64, global_load_lds w=16,
// source-side XOR swizzle, 4 waves x (4x4) 16x16x32 MFMA.
__launch_bounds__(256, 2)
__global__ void k_xproj(const unsigned short* __restrict__ xb,
                        const unsigned short* __restrict__ wib,
                        const float* __restrict__ bs,
                        unsigned short* __restrict__ xpT) {
  __shared__ __align__(16) unsigned short ldsW[2][128 * 64];
  __shared__ __align__(16) unsigned short ldsX[2][128 * 64];

  const int tid  = threadIdx.x;
  const int lane = tid & 63;
  const int w    = tid >> 6;
  const int nt   = blockIdx.x & 31;
  const int mt   = blockIdx.x >> 5;
  const int n0   = nt * 128;
  const int m0   = mt * 128;
  const int col  = lane & 15;
  const int kq   = lane >> 4;

  const int srow = lane >> 3;
  const int swzu = (lane & 7) ^ srow;

  const unsigned short* wsrc = wib + (size_t)n0 * 1024;
  const unsigned short* xsrc = xb  + (size_t)m0 * 1024;

  const int wm = (w & 1) * 64;
  const int wn = (w >> 1) * 64;

  f32x4 acc[4][4];
#pragma unroll
  for (int i = 0; i < 4; ++i)
#pragma unroll
    for (int j = 0; j < 4; ++j) acc[i][j] = (f32x4){0.f, 0.f, 0.f, 0.f};

  auto STAGE = [&](int b, int kt) {
#pragma unroll
    for (int q = 0; q < 4; ++q) {
      const int rbase = q * 32 + w * 8;
      const size_t goff = (size_t)(rbase + srow) * 1024 + kt * 64 + swzu * 8;
      gl_lds16(wsrc + goff, &ldsW[b][rbase * 64]);
      gl_lds16(xsrc + goff, &ldsX[b][rbase * 64]);
    }
  };

  STAGE(0, 0);
  int buf = 0;
  for (int kt = 0; kt < 16; ++kt) {
    asm volatile("s_waitcnt vmcnt(0)" ::: "memory");
    __syncthreads();
    if (kt < 15) STAGE(buf ^ 1, kt + 1);
#pragma unroll
    for (int ks = 0; ks < 2; ++ks) {
      bf16x8 af[4], bfr[4];
#pragma unroll
      for (int mm = 0; mm < 4; ++mm) {
        const int row = wm + mm * 16 + col;
        const int un  = (ks * 4 + kq) ^ (row & 7);
        af[mm] = *(const bf16x8*)&ldsX[buf][row * 64 + un * 8];
      }
#pragma unroll
      for (int nn = 0; nn < 4; ++nn) {
        const int row = wn + nn * 16 + col;
        const int un  = (ks * 4 + kq) ^ (row & 7);
        bfr[nn] = *(const bf16x8*)&ldsW[buf][row * 64 + un * 8];
      }
#pragma unroll
      for (int mm = 0; mm < 4; ++mm)
#pragma unroll
        for (int nn = 0; nn < 4; ++nn)
          acc[mm][nn] = __builtin_amdgcn_mfma_f32_16x16x32_bf16(
              af[mm], bfr[nn], acc[mm][nn], 0, 0, 0);
    }
    __syncthreads();
    buf ^= 1;
  }

#pragma unroll
  for (int nn = 0; nn < 4; ++nn) {
    const int nrow = n0 + wn + nn * 16 + col;
    const float bias = bs[nrow];
#pragma unroll
    for (int mm = 0; mm < 4; ++mm) {
      bf16x4 ov;
#pragma unroll
      for (int r = 0; r < 4; ++r) ov[r] = (short)f2bf(acc[mm][nn][r] + bias);
      *(bf16x4*)(xpT + (size_t)nrow * 32768 + m0 + wm + mm * 16 + kq * 4) = ov;
    }
  }
}

// ---------------------------------------------------------------------------
// Persistent recurrent kernel. grid 256 = 4 batch-rows x 64 h-col slices.
// Wave w = gate w. W_hh slice in 128 VGPR/wave. h via self-tagged u32 ring.
__launch_bounds__(256, 1)
__global__ void k_lstm(const unsigned short* __restrict__ whb,
                       const unsigned short* __restrict__ xpT,
                       const float* __restrict__ c0,
                       unsigned int* __restrict__ ring32,
                       float* __restrict__ out) {
  const int tid  = threadIdx.x;
  const int lane = tid & 63;
  const int w    = tid >> 6;            // gate index 0..3
  const int jsl  = blockIdx.x & 63;     // h-col slice
  const int brow = blockIdx.x >> 6;     // batch row 0..3
  const int b0   = brow * 16;
  const int j0   = jsl * 16;
  const int col  = lane & 15;
  const int kq   = lane >> 4;           // 0..3
  const int kch  = kq * 8;

  // hbf[buf]: 16 rows x 1024 bf16, XOR-swizzled (unit u -> u^(row&7)) for
  // conflict-free ds_read_b128 A-frags. 64 KB total.
  __shared__ __align__(16) char hbf[2][16 * 2048];
  __shared__ float glds[4][16][17];

  // W_hh slice in registers: wave w needs W[gate w][j0+col][k], 32 x bf16x8.
  bf16x8 Wr[32];
  {
    const unsigned short* wp = whb + (size_t)(w * 1024 + j0 + col) * 1024 + kch;
#pragma unroll
    for (int s = 0; s < 32; ++s) Wr[s] = *(const bf16x8*)(wp + s * 32);
  }

  const int bl = tid >> 4, cc = tid & 15;
  float c = c0[(b0 + bl) * 1024 + j0 + cc];

  const unsigned short* xprow =
      xpT + (size_t)(w * 1024 + j0 + col) * 32768 + b0 + kq * 4;
  bf16x4 xv = *(const bf16x4*)(xprow);  // step-0 x-proj slice

  // staging geometry: wave w stages local rows w*4 .. w*4+3; lane covers
  // 64 u32 cols at colbase = (lane&15)*64, as 16 chunks of u32x4.
  const int srow = w * 4 + kq;          // local batch row this lane stages
  const int swr  = srow & 7;
  const unsigned int* sb0 =
      ring32 + (size_t)(b0 + srow) * 1024 + col * 64;
  char* const hrow_base = (char*)0;  // (addresses computed per chunk below)

  // ---- stage one ring slot into hbf[buf]: poll tagged u32s, selective
  // reload of stale chunks, pack hi16 pairs -> bf16, swizzled ds_write_b64.
  auto STAGE_H = [&](const unsigned int* sb, unsigned int tg, char* hb) {
    unsigned int pend = 0xFFFFu;
    u32x4 q[16];
    for (;;) {
#pragma unroll
      for (int cchunk = 0; cchunk < 16; ++cchunk)
        if (pend & (1u << cchunk)) q[cchunk] = llc_load4(sb + cchunk * 4);
      asm volatile("s_waitcnt vmcnt(0)" ::: "memory");
      __builtin_amdgcn_sched_barrier(0);
#pragma unroll
      for (int cchunk = 0; cchunk < 16; ++cchunk) {
        if (pend & (1u << cchunk)) {
          unsigned int bad = ((q[cchunk][0] ^ tg) | (q[cchunk][1] ^ tg) |
                              (q[cchunk][2] ^ tg) | (q[cchunk][3] ^ tg)) & 0xFFFFu;
          if (bad == 0u) {
            unsigned int lo = (q[cchunk][0] >> 16) | (q[cchunk][1] & 0xFFFF0000u);
            unsigned int hi = (q[cchunk][2] >> 16) | (q[cchunk][3] & 0xFFFF0000u);
            const int u = (col * 8 + (cchunk >> 1)) ^ swr;
            u64 pk = (u64)lo | ((u64)hi << 32);
            *(u64*)(hb + srow * 2048 + u * 16 + (cchunk & 1) * 8) = pk;
            pend &= ~(1u << cchunk);
          }
        }
      }
      if (__all(pend == 0u)) break;
    }
  };

  (void)hrow_base;
  STAGE_H(sb0, 0u, hbf[0]);  // slot 0 = h0 (tag 0)

  const int swz = col & 7;   // A-frag row swizzle (row = col)

  for (int t = 0; t < T_STEPS; ++t) {
    __syncthreads();  // B1: hbf[t&1] staged by all waves; glds safe to rewrite

    // ---- recurrent GEMM: gate w, C[16b x 16j], K=1024, A from swizzled LDS
    const char* hb = hbf[t & 1];
    f32x4 acc0 = (f32x4){0.f, 0.f, 0.f, 0.f};
    f32x4 acc1 = (f32x4){0.f, 0.f, 0.f, 0.f};
#pragma unroll
    for (int s = 0; s < 32; s += 2) {
      bf16x8 a0 = *(const bf16x8*)(hb + col * 2048 + (((s * 4 + kq) ^ swz) * 16));
      bf16x8 a1 = *(const bf16x8*)(hb + col * 2048 + ((((s + 1) * 4 + kq) ^ swz) * 16));
      acc0 = __builtin_amdgcn_mfma_f32_16x16x32_bf16(a0, Wr[s],     acc0, 0, 0, 0);
      acc1 = __builtin_amdgcn_mfma_f32_16x16x32_bf16(a1, Wr[s + 1], acc1, 0, 0, 0);
    }

#pragma unroll
    for (int r = 0; r < 4; ++r) {
      float v = (acc0[r] + acc1[r]) + bf2f(xv[r]);
      float g = (w == 2) ? tanh_f(v) : sigm(v);
      glds[w][kq * 4 + r][col] = g;
    }
    __syncthreads();  // B2

    float ig = glds[0][bl][cc], fg = glds[1][bl][cc];
    float gg = glds[2][bl][cc], og = glds[3][bl][cc];
    c = fg * c + ig * gg;
    float h = og * tanh_f(c);

    // ---- publish h as self-tagged u32: fire-and-forget, no drain, no flag
    if (t < T_STEPS - 1) {
      unsigned int pk = ((unsigned int)f2bf(h) << 16) | (unsigned int)(t + 1);
      __hip_atomic_store(ring32 + (size_t)((t + 1) & (NSLOT - 1)) * BH +
                             (b0 + bl) * 1024 + (j0 + cc),
                         pk, __ATOMIC_RELAXED, __HIP_MEMORY_SCOPE_AGENT);
    }

    // ---- outputs (off the critical path)
    const int hoff = (b0 + bl) * 1024 + j0 + cc;
    out[(size_t)t * BH + hoff] = h;
    if (t == T_STEPS - 1) {
      out[(size_t)T_STEPS * BH + hoff] = h;       // hT
      out[(size_t)T_STEPS * BH + BH + hoff] = c;  // cT
    } else {
      // prefetch next x-proj slice, then stage ring slot t+1 into hbf[(t+1)&1]
      xv = *(const bf16x4*)(xprow + (size_t)(t + 1) * 64);
      STAGE_H(sb0 + (size_t)((t + 1) & (NSLOT - 1)) * BH,
              (unsigned int)(t + 1), hbf[(t + 1) & 1]);
    }
  }
}

// ---------------------------------------------------------------------------
extern "C" void kernel_launch(void* const* d_in, const int* in_sizes, int n_in,
                              void* d_out, int out_size, void* d_ws, size_t ws_size,
                              hipStream_t stream) {
  const float* x   = (const float*)d_in[0];
  const float* h0  = (const float*)d_in[1];
  const float* c0  = (const float*)d_in[2];
  const float* Wih = (const float*)d_in[3];
  const float* Whh = (const float*)d_in[4];
  const float* bih = (const float*)d_in[5];
  const float* bhh = (const float*)d_in[6];
  float* out = (float*)d_out;
  char* ws = (char*)d_ws;

  unsigned short* xpT  = (unsigned short*)(ws + OFF_XPT);
  unsigned int*   ring = (unsigned int*)(ws + OFF_RING);
  unsigned short* wib  = (unsigned short*)(ws + OFF_WIB);
  unsigned short* whb  = (unsigned short*)(ws + OFF_WHB);
  float*          bsum = (float*)(ws + OFF_BSUM);

  // bf16 x lives in d_out's first 64MB: fully consumed by k_xproj before
  // k_lstm starts writing outputs (kernels are stream-ordered).
  unsigned short* xb = (unsigned short*)d_out;

  k_cast_bf16<<<dim3(32768), dim3(256), 0, stream>>>(x, xb, T_STEPS * BATCH * HID);
  k_cast_bf16<<<dim3(4096),  dim3(256), 0, stream>>>(Wih, wib, G4 * HID);
  k_cast_bf16<<<dim3(4096),  dim3(256), 0, stream>>>(Whh, whb, G4 * HID);
  k_h0_pack<<<dim3(256),     dim3(256), 0, stream>>>(h0, ring);  // slot 0, tag 0
  k_bias<<<dim3(16), dim3(256), 0, stream>>>(bih, bhh, bsum);

  k_xproj<<<dim3(8192), dim3(256), 0, stream>>>(xb, wib, bsum, xpT);
  k_lstm<<<dim3(256), dim3(256), 0, stream>>>(whb, xpT, c0, ring, out);
}

// Round 3
// 3214.134 us; speedup vs baseline: 1.5727x; 1.5727x over previous
//
#include <hip/hip_runtime.h>

// ---------------------------------------------------------------------------
// LSTM layer, T=512 B=64 I=H=1024, bf16 MFMA path.
// d_in: x[T,B,I], h0[B,H], c0[B,H], W_ih[4H,I], W_hh[4H,H], b_ih[4H], b_hh[4H]
// d_out: outputs[T,B,H] ++ hT[B,H] ++ cT[B,H]  (fp32)
//
// Round 6:
//  - Tagged-word h exchange kept (no drain / no flag / no flag-poll), but the
//    two R5 regressions fixed:
//      * LDS staging is FRAG-MAJOR: hbf[s][lane] 16B frags. Staging lane l
//        packs exactly the frag consumer-lane l reads -> both ds_write_b128
//        and ds_read_b128 are linear (conflict-free). No swizzle at all.
//        (R5's layout was a 16-way write conflict: 578M conflict cycles.)
//      * Tagged loads are coalesced (8 contiguous u32/lane/chunk) and the
//        FIRST pass is normal cached loads (L2 dedup on-XCD); only retries
//        of stale chunks bypass with sc0 sc1. Tags catch any staleness.
//  - Ring = 64 slots x 64x1024 u32 = 16 MB (memset once; tag t+1 unique over
//    512 steps; slot-reuse distance 64 >> L1/L2 residency).
//  - Publish: one relaxed agent-scope u32 store per thread, fire-and-forget.
//  - 2 barriers/step, single LDS A-buffer (stage(t+1) is after B2 by
//    construction since it follows our own publish).
//  - k_xproj unchanged (verified m97 structure).
// ---------------------------------------------------------------------------

typedef __attribute__((ext_vector_type(8))) short bf16x8;
typedef __attribute__((ext_vector_type(4))) short bf16x4;
typedef __attribute__((ext_vector_type(4))) float f32x4;
typedef __attribute__((ext_vector_type(4))) unsigned int u32x4;
typedef unsigned long long u64;

#define T_STEPS 512
#define BATCH   64
#define HID     1024
#define G4      4096
#define BH      (BATCH * HID)
#define NSLOT   64

// ws layout (bytes)
#define OFF_XPT   ((size_t)0)            // bf16 [4096][32768] transposed x-proj (+bias)
#define OFF_RING  ((size_t)268435456)    // u32 [64][64][1024] tagged h ring (16 MB)
#define OFF_WIB   ((size_t)335544320)    // bf16 [4096][1024] W_ih
#define OFF_WHB   ((size_t)343932928)    // bf16 [4096][1024] W_hh
#define OFF_BSUM  ((size_t)352321536)    // f32 [4096] b_ih+b_hh

__device__ __forceinline__ unsigned short f2bf(float f) {
  unsigned int u = __float_as_uint(f);
  u += 0x7FFFu + ((u >> 16) & 1u);
  return (unsigned short)(u >> 16);
}
__device__ __forceinline__ float bf2f(short s) {
  return __uint_as_float(((unsigned int)(unsigned short)s) << 16);
}
__device__ __forceinline__ float sigm(float x) { return 1.0f / (1.0f + __expf(-x)); }
__device__ __forceinline__ float tanh_f(float x) {
  float e = __expf(-2.0f * fabsf(x));
  float r = (1.0f - e) / (1.0f + e);
  return x < 0.0f ? -r : r;
}

// async global->LDS, 16B per lane. LDS dest is wave-uniform base + lane*16.
__device__ __forceinline__ void gl_lds16(const unsigned short* g, unsigned short* l) {
  __builtin_amdgcn_global_load_lds(
      (const __attribute__((address_space(1))) unsigned int*)g,
      (__attribute__((address_space(3))) unsigned int*)l, 16, 0, 0);
}

// LLC-coherent 16B load (sc0 sc1: bypass L1+L2). Caller batches, then
// waitcnt vmcnt(0) + sched_barrier(0) before reading results (rule #18).
__device__ __forceinline__ u32x4 llc_load4(const unsigned int* p) {
  u32x4 r;
  asm volatile("global_load_dwordx4 %0, %1, off sc0 sc1"
               : "=&v"(r) : "v"(p));
  return r;
}

// ---------------------------------------------------------------------------
__global__ void k_cast_bf16(const float* __restrict__ src,
                            unsigned short* __restrict__ dst, int n) {
  int i = (blockIdx.x * 256 + threadIdx.x) * 4;
  if (i >= n) return;
  float4 v = *(const float4*)(src + i);
  bf16x4 o;
  o[0] = (short)f2bf(v.x); o[1] = (short)f2bf(v.y);
  o[2] = (short)f2bf(v.z); o[3] = (short)f2bf(v.w);
  *(bf16x4*)(dst + i) = o;
}

__global__ void k_bias(const float* __restrict__ bi, const float* __restrict__ bh,
                       float* __restrict__ bs) {
  int i = blockIdx.x * 256 + threadIdx.x;
  if (i < G4) bs[i] = bi[i] + bh[i];
}

// h0 -> ring slot 0 as tagged u32 (tag 1). Agent-scope write-through so the
// data lands in LLC (k_lstm bypass retries read LLC directly).
__global__ void k_h0_pack(const float* __restrict__ h0,
                          unsigned int* __restrict__ ring32) {
  int i = blockIdx.x * 256 + threadIdx.x;
  unsigned int pk = ((unsigned int)f2bf(h0[i]) << 16) | 1u;
  __hip_atomic_store(ring32 + i, pk, __ATOMIC_RELAXED, __HIP_MEMORY_SCOPE_AGENT);
}

// ---------------------------------------------------------------------------
// x-projection GEMM: xpT[n][m] = sum_k xb[m][k]*wib[n][k] + bsum[n]  (bf16 out)
// Verified m97 structure (round 4): 128x128 tile, BK=64, global_load_lds w=16,
// source-side XOR swizzle, 4 waves x (4x4) 16x16x32 MFMA.
__launch_bounds__(256, 2)
__global__ void k_xproj(const unsigned short* __restrict__ xb,
                        const unsigned short* __restrict__ wib,
                        const float* __restrict__ bs,
                        unsigned short* __restrict__ xpT) {
  __shared__ __align__(16) unsigned short ldsW[2][128 * 64];
  __shared__ __align__(16) unsigned short ldsX[2][128 * 64];

  const int tid  = threadIdx.x;
  const int lane = tid & 63;
  const int w    = tid >> 6;
  const int nt   = blockIdx.x & 31;
  const int mt   = blockIdx.x >> 5;
  const int n0   = nt * 128;
  const int m0   = mt * 128;
  const int col  = lane & 15;
  const int kq   = lane >> 4;

  const int srow = lane >> 3;
  const int swzu = (lane & 7) ^ srow;

  const unsigned short* wsrc = wib + (size_t)n0 * 1024;
  const unsigned short* xsrc = xb  + (size_t)m0 * 1024;

  const int wm = (w & 1) * 64;
  const int wn = (w >> 1) * 64;

  f32x4 acc[4][4];
#pragma unroll
  for (int i = 0; i < 4; ++i)
#pragma unroll
    for (int j = 0; j < 4; ++j) acc[i][j] = (f32x4){0.f, 0.f, 0.f, 0.f};

  auto STAGE = [&](int b, int kt) {
#pragma unroll
    for (int q = 0; q < 4; ++q) {
      const int rbase = q * 32 + w * 8;
      const size_t goff = (size_t)(rbase + srow) * 1024 + kt * 64 + swzu * 8;
      gl_lds16(wsrc + goff, &ldsW[b][rbase * 64]);
      gl_lds16(xsrc + goff, &ldsX[b][rbase * 64]);
    }
  };

  STAGE(0, 0);
  int buf = 0;
  for (int kt = 0; kt < 16; ++kt) {
    asm volatile("s_waitcnt vmcnt(0)" ::: "memory");
    __syncthreads();
    if (kt < 15) STAGE(buf ^ 1, kt + 1);
#pragma unroll
    for (int ks = 0; ks < 2; ++ks) {
      bf16x8 af[4], bfr[4];
#pragma unroll
      for (int mm = 0; mm < 4; ++mm) {
        const int row = wm + mm * 16 + col;
        const int un  = (ks * 4 + kq) ^ (row & 7);
        af[mm] = *(const bf16x8*)&ldsX[buf][row * 64 + un * 8];
      }
#pragma unroll
      for (int nn = 0; nn < 4; ++nn) {
        const int row = wn + nn * 16 + col;
        const int un  = (ks * 4 + kq) ^ (row & 7);
        bfr[nn] = *(const bf16x8*)&ldsW[buf][row * 64 + un * 8];
      }
#pragma unroll
      for (int mm = 0; mm < 4; ++mm)
#pragma unroll
        for (int nn = 0; nn < 4; ++nn)
          acc[mm][nn] = __builtin_amdgcn_mfma_f32_16x16x32_bf16(
              af[mm], bfr[nn], acc[mm][nn], 0, 0, 0);
    }
    __syncthreads();
    buf ^= 1;
  }

#pragma unroll
  for (int nn = 0; nn < 4; ++nn) {
    const int nrow = n0 + wn + nn * 16 + col;
    const float bias = bs[nrow];
#pragma unroll
    for (int mm = 0; mm < 4; ++mm) {
      bf16x4 ov;
#pragma unroll
      for (int r = 0; r < 4; ++r) ov[r] = (short)f2bf(acc[mm][nn][r] + bias);
      *(bf16x4*)(xpT + (size_t)nrow * 32768 + m0 + wm + mm * 16 + kq * 4) = ov;
    }
  }
}

// ---------------------------------------------------------------------------
// Persistent recurrent kernel. grid 256 = 4 batch-rows x 64 h-col slices.
// Wave w = gate w. W_hh slice in 128 VGPR/wave. h via self-tagged u32 ring,
// staged into frag-major LDS (linear, conflict-free both sides).
__launch_bounds__(256, 1)
__global__ void k_lstm(const unsigned short* __restrict__ whb,
                       const unsigned short* __restrict__ xpT,
                       const float* __restrict__ c0,
                       unsigned int* __restrict__ ring32,
                       float* __restrict__ out) {
  const int tid  = threadIdx.x;
  const int lane = tid & 63;
  const int w    = tid >> 6;            // gate index 0..3
  const int jsl  = blockIdx.x & 63;     // h-col slice
  const int brow = blockIdx.x >> 6;     // batch row 0..3
  const int b0   = brow * 16;
  const int j0   = jsl * 16;
  const int col  = lane & 15;           // consumer A row within tile
  const int kq   = lane >> 4;           // 0..3
  const int kch  = kq * 8;

  // frag-major A buffer: hbf[s][lane] 16B bf16x8 frags, s = 0..31. 32 KB.
  __shared__ __align__(16) unsigned char hbf[32 * 1024];
  __shared__ float glds[4][16][17];

  // W_hh slice in registers: wave w needs W[gate w][j0+col][k], 32 x bf16x8.
  bf16x8 Wr[32];
  {
    const unsigned short* wp = whb + (size_t)(w * 1024 + j0 + col) * 1024 + kch;
#pragma unroll
    for (int s = 0; s < 32; ++s) Wr[s] = *(const bf16x8*)(wp + s * 32);
  }

  const int bl = tid >> 4, cc = tid & 15;
  float c = c0[(b0 + bl) * 1024 + j0 + cc];

  const unsigned short* xprow =
      xpT + (size_t)(w * 1024 + j0 + col) * 32768 + b0 + kq * 4;
  bf16x4 xv = *(const bf16x4*)(xprow);  // step-0 x-proj slice

  // per-lane tagged-ring base: row (b0+col), k offset kq*8 (u32 units).
  const size_t lrow = (size_t)(b0 + col) * 1024 + kq * 8;

  // Stage one ring slot into hbf. Wave w handles s in [w*8, w*8+8).
  // Lane l packs the frag consumer-lane l reads: row b0+(l&15), k s*32+(l>>4)*8.
  // First pass cached; stale chunks retried with sc0 sc1 (LLC-fresh).
  auto STAGE_H = [&](size_t slotbase, unsigned int tg) {
    const unsigned int* sb = ring32 + slotbase + lrow;
    u32x4 q0[8], q1[8];
#pragma unroll
    for (int i = 0; i < 8; ++i) {
      q0[i] = *(const u32x4*)(sb + (w * 8 + i) * 32);
      q1[i] = *(const u32x4*)(sb + (w * 8 + i) * 32 + 4);
    }
    unsigned int pend = 0xFFu;
    for (;;) {
#pragma unroll
      for (int i = 0; i < 8; ++i)
        if (pend & (1u << i)) {
          unsigned int bad =
              ((q0[i][0] ^ tg) | (q0[i][1] ^ tg) | (q0[i][2] ^ tg) | (q0[i][3] ^ tg) |
               (q1[i][0] ^ tg) | (q1[i][1] ^ tg) | (q1[i][2] ^ tg) | (q1[i][3] ^ tg)) &
              0xFFFFu;
          if (bad == 0u) {
            u32x4 o;   // pack 8 hi16 payloads -> bf16x8 (4 u32)
            o[0] = (q0[i][0] >> 16) | (q0[i][1] & 0xFFFF0000u);
            o[1] = (q0[i][2] >> 16) | (q0[i][3] & 0xFFFF0000u);
            o[2] = (q1[i][0] >> 16) | (q1[i][1] & 0xFFFF0000u);
            o[3] = (q1[i][2] >> 16) | (q1[i][3] & 0xFFFF0000u);
            *(u32x4*)(hbf + (w * 8 + i) * 1024 + lane * 16) = o;  // linear write
            pend &= ~(1u << i);
          }
        }
      if (__all(pend == 0u)) break;
#pragma unroll
      for (int i = 0; i < 8; ++i)
        if (pend & (1u << i)) {
          q0[i] = llc_load4(sb + (w * 8 + i) * 32);
          q1[i] = llc_load4(sb + (w * 8 + i) * 32 + 4);
        }
      asm volatile("s_waitcnt vmcnt(0)" ::: "memory");
      __builtin_amdgcn_sched_barrier(0);
    }
  };

  STAGE_H(0, 1u);  // slot 0 = h0, tag 1

  for (int t = 0; t < T_STEPS; ++t) {
    __syncthreads();  // B1: hbf staged by all waves

    // ---- recurrent GEMM: gate w, C[16b x 16j], K=1024, linear frag reads
    f32x4 acc0 = (f32x4){0.f, 0.f, 0.f, 0.f};
    f32x4 acc1 = (f32x4){0.f, 0.f, 0.f, 0.f};
#pragma unroll
    for (int s = 0; s < 32; s += 2) {
      bf16x8 a0 = *(const bf16x8*)(hbf + s * 1024 + lane * 16);
      bf16x8 a1 = *(const bf16x8*)(hbf + (s + 1) * 1024 + lane * 16);
      acc0 = __builtin_amdgcn_mfma_f32_16x16x32_bf16(a0, Wr[s],     acc0, 0, 0, 0);
      acc1 = __builtin_amdgcn_mfma_f32_16x16x32_bf16(a1, Wr[s + 1], acc1, 0, 0, 0);
    }

#pragma unroll
    for (int r = 0; r < 4; ++r) {
      float v = (acc0[r] + acc1[r]) + bf2f(xv[r]);
      float g = (w == 2) ? tanh_f(v) : sigm(v);
      glds[w][kq * 4 + r][col] = g;
    }
    __syncthreads();  // B2: glds ready; hbf reads done -> restage allowed

    float ig = glds[0][bl][cc], fg = glds[1][bl][cc];
    float gg = glds[2][bl][cc], og = glds[3][bl][cc];
    c = fg * c + ig * gg;
    float h = og * tanh_f(c);

    // ---- publish h(t+1) tagged (t+2): one store, fire-and-forget ----------
    if (t < T_STEPS - 1) {
      unsigned int pk = ((unsigned int)f2bf(h) << 16) | (unsigned int)(t + 2);
      __hip_atomic_store(ring32 + (size_t)((t + 1) & (NSLOT - 1)) * BH +
                             (size_t)(b0 + bl) * 1024 + (j0 + cc),
                         pk, __ATOMIC_RELAXED, __HIP_MEMORY_SCOPE_AGENT);
    }

    // ---- outputs (off the critical path) ----------------------------------
    const int hoff = (b0 + bl) * 1024 + j0 + cc;
    out[(size_t)t * BH + hoff] = h;
    if (t == T_STEPS - 1) {
      out[(size_t)T_STEPS * BH + hoff] = h;       // hT
      out[(size_t)T_STEPS * BH + BH + hoff] = c;  // cT
    } else {
      xv = *(const bf16x4*)(xprow + (size_t)(t + 1) * 64);
      STAGE_H((size_t)((t + 1) & (NSLOT - 1)) * BH, (unsigned int)(t + 2));
    }
  }
}

// ---------------------------------------------------------------------------
extern "C" void kernel_launch(void* const* d_in, const int* in_sizes, int n_in,
                              void* d_out, int out_size, void* d_ws, size_t ws_size,
                              hipStream_t stream) {
  const float* x   = (const float*)d_in[0];
  const float* h0  = (const float*)d_in[1];
  const float* c0  = (const float*)d_in[2];
  const float* Wih = (const float*)d_in[3];
  const float* Whh = (const float*)d_in[4];
  const float* bih = (const float*)d_in[5];
  const float* bhh = (const float*)d_in[6];
  float* out = (float*)d_out;
  char* ws = (char*)d_ws;

  unsigned short* xpT  = (unsigned short*)(ws + OFF_XPT);
  unsigned int*   ring = (unsigned int*)(ws + OFF_RING);
  unsigned short* wib  = (unsigned short*)(ws + OFF_WIB);
  unsigned short* whb  = (unsigned short*)(ws + OFF_WHB);
  float*          bsum = (float*)(ws + OFF_BSUM);

  // bf16 x lives in d_out's first 64MB: fully consumed by k_xproj before
  // k_lstm starts writing outputs (kernels are stream-ordered).
  unsigned short* xb = (unsigned short*)d_out;

  hipMemsetAsync(ring, 0, (size_t)NSLOT * BH * sizeof(unsigned int), stream);

  k_cast_bf16<<<dim3(32768), dim3(256), 0, stream>>>(x, xb, T_STEPS * BATCH * HID);
  k_cast_bf16<<<dim3(4096),  dim3(256), 0, stream>>>(Wih, wib, G4 * HID);
  k_cast_bf16<<<dim3(4096),  dim3(256), 0, stream>>>(Whh, whb, G4 * HID);
  k_h0_pack<<<dim3(256),     dim3(256), 0, stream>>>(h0, ring);  // slot 0, tag 1
  k_bias<<<dim3(16), dim3(256), 0, stream>>>(bih, bhh, bsum);

  k_xproj<<<dim3(8192), dim3(256), 0, stream>>>(xb, wib, bsum, xpT);
  k_lstm<<<dim3(256), dim3(256), 0, stream>>>(whb, xpT, c0, ring, out);
}

// Round 4
// 2925.378 us; speedup vs baseline: 1.7279x; 1.0987x over previous
//
#include <hip/hip_runtime.h>

// ---------------------------------------------------------------------------
// LSTM layer, T=512 B=64 I=H=1024, bf16 MFMA path.
// d_in: x[T,B,I], h0[B,H], c0[B,H], W_ih[4H,I], W_hh[4H,H], b_ih[4H], b_hh[4H]
// d_out: outputs[T,B,H] ++ hT[B,H] ++ cT[B,H]  (fp32)
//
// Round 7:
//  - k_xproj ELIMINATED: x-projection fused into k_lstm with a 2-step
//    lookahead. Each block computes exactly its own 1/256 xproj slice
//    (no cross-block dep), and the MFMA D-layout puts xp[m=kq*4+r][n=col]
//    in precisely the lane/reg slots the gate calc consumes -> zero shuffle,
//    f32 precision (no xpT bf16 round-trip), no 256MB xpT write+read.
//    32 extra MFMA/wave/step + 8 global_load_lds x-gathers, executed in the
//    exchange wait-bubble right after the h publish.
//  - W_ih slice joins W_hh in VGPRs (32+32 bf16x8 = 256 regs of weights).
//  - x staged frag-major into double-buffered xlds via per-lane-source
//    global_load_lds (consumed 2 steps later; barriers cover the latency).
//  - Exchange unchanged from round 6 (tagged u32 ring, cached first pass,
//    sc0 sc1 bypass retries, frag-major hbf -- verified 578M->8.4M conflicts).
// ---------------------------------------------------------------------------

typedef __attribute__((ext_vector_type(8))) short bf16x8;
typedef __attribute__((ext_vector_type(4))) short bf16x4;
typedef __attribute__((ext_vector_type(4))) float f32x4;
typedef __attribute__((ext_vector_type(4))) unsigned int u32x4;
typedef unsigned long long u64;

#define T_STEPS 512
#define BATCH   64
#define HID     1024
#define G4      4096
#define BH      (BATCH * HID)
#define NSLOT   64

// ws layout (bytes)
#define OFF_XB    ((size_t)0)            // bf16 [512][64][1024] x (64 MB)
#define OFF_RING  ((size_t)268435456)    // u32 [64][64][1024] tagged h ring (16 MB)
#define OFF_WIB   ((size_t)335544320)    // bf16 [4096][1024] W_ih
#define OFF_WHB   ((size_t)343932928)    // bf16 [4096][1024] W_hh
#define OFF_BSUM  ((size_t)352321536)    // f32 [4096] b_ih+b_hh

__device__ __forceinline__ unsigned short f2bf(float f) {
  unsigned int u = __float_as_uint(f);
  u += 0x7FFFu + ((u >> 16) & 1u);
  return (unsigned short)(u >> 16);
}
__device__ __forceinline__ float sigm(float x) { return 1.0f / (1.0f + __expf(-x)); }
__device__ __forceinline__ float tanh_f(float x) {
  float e = __expf(-2.0f * fabsf(x));
  float r = (1.0f - e) / (1.0f + e);
  return x < 0.0f ? -r : r;
}

// async global->LDS, 16B per lane. LDS dest = wave-uniform base + lane*16;
// global source address is PER-LANE (m104/m173).
__device__ __forceinline__ void gl_lds16(const unsigned short* g, unsigned short* l) {
  __builtin_amdgcn_global_load_lds(
      (const __attribute__((address_space(1))) unsigned int*)g,
      (__attribute__((address_space(3))) unsigned int*)l, 16, 0, 0);
}

// LLC-coherent 16B load (sc0 sc1: bypass L1+L2). Caller batches, then
// waitcnt vmcnt(0) + sched_barrier(0) before reading results (rule #18).
__device__ __forceinline__ u32x4 llc_load4(const unsigned int* p) {
  u32x4 r;
  asm volatile("global_load_dwordx4 %0, %1, off sc0 sc1"
               : "=&v"(r) : "v"(p));
  return r;
}

// ---------------------------------------------------------------------------
__global__ void k_cast_bf16(const float* __restrict__ src,
                            unsigned short* __restrict__ dst, int n) {
  int i = (blockIdx.x * 256 + threadIdx.x) * 4;
  if (i >= n) return;
  float4 v = *(const float4*)(src + i);
  bf16x4 o;
  o[0] = (short)f2bf(v.x); o[1] = (short)f2bf(v.y);
  o[2] = (short)f2bf(v.z); o[3] = (short)f2bf(v.w);
  *(bf16x4*)(dst + i) = o;
}

__global__ void k_bias(const float* __restrict__ bi, const float* __restrict__ bh,
                       float* __restrict__ bs) {
  int i = blockIdx.x * 256 + threadIdx.x;
  if (i < G4) bs[i] = bi[i] + bh[i];
}

// h0 -> ring slot 0 as tagged u32 (tag 1). Agent-scope write-through.
__global__ void k_h0_pack(const float* __restrict__ h0,
                          unsigned int* __restrict__ ring32) {
  int i = blockIdx.x * 256 + threadIdx.x;
  unsigned int pk = ((unsigned int)f2bf(h0[i]) << 16) | 1u;
  __hip_atomic_store(ring32 + i, pk, __ATOMIC_RELAXED, __HIP_MEMORY_SCOPE_AGENT);
}

// ---------------------------------------------------------------------------
// Persistent fused kernel. grid 256 = 4 batch-rows x 64 h-col slices.
// Wave w = gate w. W_hh + W_ih slices in VGPRs. h via self-tagged u32 ring,
// staged into frag-major LDS. x-projection computed in-block, 2 steps ahead.
__launch_bounds__(256, 1)
__global__ void k_lstm(const unsigned short* __restrict__ whb,
                       const unsigned short* __restrict__ wib,
                       const unsigned short* __restrict__ xb,
                       const float* __restrict__ bs,
                       const float* __restrict__ c0,
                       unsigned int* __restrict__ ring32,
                       float* __restrict__ out) {
  const int tid  = threadIdx.x;
  const int lane = tid & 63;
  const int w    = tid >> 6;            // gate index 0..3
  const int jsl  = blockIdx.x & 63;     // h-col slice
  const int brow = blockIdx.x >> 6;     // batch row 0..3
  const int b0   = brow * 16;
  const int j0   = jsl * 16;
  const int col  = lane & 15;
  const int kq   = lane >> 4;           // 0..3
  const int kch  = kq * 8;

  // frag-major buffers: [s][lane] 16B bf16x8 frags, s = 0..31.
  __shared__ __align__(16) unsigned char hbf[32 * 1024];        // h(t)   32 KB
  __shared__ __align__(16) unsigned char xlds[2][32 * 1024];    // x      64 KB
  __shared__ float glds[4][16][17];

  // Weight slices in registers: wave w, rows n = w*1024 + j0 + col.
  bf16x8 Wh[32], Wi[32];
  {
    const unsigned short* wph = whb + (size_t)(w * 1024 + j0 + col) * 1024 + kch;
    const unsigned short* wpi = wib + (size_t)(w * 1024 + j0 + col) * 1024 + kch;
#pragma unroll
    for (int s = 0; s < 32; ++s) {
      Wh[s] = *(const bf16x8*)(wph + s * 32);
      Wi[s] = *(const bf16x8*)(wpi + s * 32);
    }
  }
  const float bias = bs[w * 1024 + j0 + col];

  const int bl = tid >> 4, cc = tid & 15;
  float c = c0[(b0 + bl) * 1024 + j0 + cc];

  // per-lane tagged-ring base: row (b0+col), k offset kq*8 (u32 units).
  const size_t lrow = (size_t)(b0 + col) * 1024 + kq * 8;

  // ---- stage one ring slot into hbf (round-6-verified exchange) ----------
  auto STAGE_H = [&](size_t slotbase, unsigned int tg) {
    const unsigned int* sb = ring32 + slotbase + lrow;
    u32x4 q0[8], q1[8];
#pragma unroll
    for (int i = 0; i < 8; ++i) {
      q0[i] = *(const u32x4*)(sb + (w * 8 + i) * 32);
      q1[i] = *(const u32x4*)(sb + (w * 8 + i) * 32 + 4);
    }
    unsigned int pend = 0xFFu;
    for (;;) {
#pragma unroll
      for (int i = 0; i < 8; ++i)
        if (pend & (1u << i)) {
          unsigned int bad =
              ((q0[i][0] ^ tg) | (q0[i][1] ^ tg) | (q0[i][2] ^ tg) | (q0[i][3] ^ tg) |
               (q1[i][0] ^ tg) | (q1[i][1] ^ tg) | (q1[i][2] ^ tg) | (q1[i][3] ^ tg)) &
              0xFFFFu;
          if (bad == 0u) {
            u32x4 o;   // pack 8 hi16 payloads -> bf16x8 (4 u32)
            o[0] = (q0[i][0] >> 16) | (q0[i][1] & 0xFFFF0000u);
            o[1] = (q0[i][2] >> 16) | (q0[i][3] & 0xFFFF0000u);
            o[2] = (q1[i][0] >> 16) | (q1[i][1] & 0xFFFF0000u);
            o[3] = (q1[i][2] >> 16) | (q1[i][3] & 0xFFFF0000u);
            *(u32x4*)(hbf + (w * 8 + i) * 1024 + lane * 16) = o;  // linear write
            pend &= ~(1u << i);
          }
        }
      if (__all(pend == 0u)) break;
#pragma unroll
      for (int i = 0; i < 8; ++i)
        if (pend & (1u << i)) {
          q0[i] = llc_load4(sb + (w * 8 + i) * 32);
          q1[i] = llc_load4(sb + (w * 8 + i) * 32 + 4);
        }
      asm volatile("s_waitcnt vmcnt(0)" ::: "memory");
      __builtin_amdgcn_sched_barrier(0);
    }
  };

  // ---- stage x[t_] frag-major into xlds[slot] (8 gl_lds per wave) --------
  auto STAGE_X = [&](int t_, int slot) {
    const unsigned short* xs = xb + ((size_t)t_ * 64 + b0 + col) * 1024 + kch;
#pragma unroll
    for (int i = 0; i < 8; ++i) {
      const int s = w * 8 + i;
      gl_lds16(xs + s * 32, (unsigned short*)(xlds[slot] + s * 1024));
    }
  };

  // ---- xproj tile for this wave from xlds[slot]: D[m=kq*4+r][n=col] ------
  auto XPROJ = [&](int slot) -> f32x4 {
    f32x4 a0 = (f32x4){0.f, 0.f, 0.f, 0.f};
    f32x4 a1 = (f32x4){0.f, 0.f, 0.f, 0.f};
#pragma unroll
    for (int s = 0; s < 32; s += 2) {
      bf16x8 x0 = *(const bf16x8*)(xlds[slot] + s * 1024 + lane * 16);
      bf16x8 x1 = *(const bf16x8*)(xlds[slot] + (s + 1) * 1024 + lane * 16);
      a0 = __builtin_amdgcn_mfma_f32_16x16x32_bf16(x0, Wi[s],     a0, 0, 0, 0);
      a1 = __builtin_amdgcn_mfma_f32_16x16x32_bf16(x1, Wi[s + 1], a1, 0, 0, 0);
    }
    return a0 + a1;
  };

  // ---- prologue pipeline --------------------------------------------------
  STAGE_H(0, 1u);            // hbf = h0 (slot 0, tag 1)
  STAGE_X(0, 0);
  STAGE_X(1, 1);
  asm volatile("s_waitcnt vmcnt(0)" ::: "memory");
  __syncthreads();
  f32x4 xv_cur = XPROJ(0);   // xv for step 0
  f32x4 xv_nxt = XPROJ(1);   // xv for step 1
  asm volatile("s_waitcnt lgkmcnt(0)" ::: "memory");
  __builtin_amdgcn_sched_barrier(0);
  STAGE_X(2, 0);             // x[2] -> slot0 (read at step 0's XPROJ)
  STAGE_X(3, 1);             // x[3] -> slot1 (read at step 1's XPROJ)

  for (int t = 0; t < T_STEPS; ++t) {
    __syncthreads();  // B1: hbf + staged x visible

    // ---- recurrent GEMM: gate w, K=1024, linear frag reads ---------------
    f32x4 acc0 = (f32x4){0.f, 0.f, 0.f, 0.f};
    f32x4 acc1 = (f32x4){0.f, 0.f, 0.f, 0.f};
#pragma unroll
    for (int s = 0; s < 32; s += 2) {
      bf16x8 a0 = *(const bf16x8*)(hbf + s * 1024 + lane * 16);
      bf16x8 a1 = *(const bf16x8*)(hbf + (s + 1) * 1024 + lane * 16);
      acc0 = __builtin_amdgcn_mfma_f32_16x16x32_bf16(a0, Wh[s],     acc0, 0, 0, 0);
      acc1 = __builtin_amdgcn_mfma_f32_16x16x32_bf16(a1, Wh[s + 1], acc1, 0, 0, 0);
    }

#pragma unroll
    for (int r = 0; r < 4; ++r) {
      float v = (acc0[r] + acc1[r]) + xv_cur[r] + bias;
      float g = (w == 2) ? tanh_f(v) : sigm(v);
      glds[w][kq * 4 + r][col] = g;
    }
    __syncthreads();  // B2: glds ready; hbf reads done -> restage allowed

    float ig = glds[0][bl][cc], fg = glds[1][bl][cc];
    float gg = glds[2][bl][cc], og = glds[3][bl][cc];
    c = fg * c + ig * gg;
    float h = og * tanh_f(c);

    // ---- publish h tagged (t+2): one store, fire-and-forget --------------
    if (t < T_STEPS - 1) {
      unsigned int pk = ((unsigned int)f2bf(h) << 16) | (unsigned int)(t + 2);
      __hip_atomic_store(ring32 + (size_t)((t + 1) & (NSLOT - 1)) * BH +
                             (size_t)(b0 + bl) * 1024 + (j0 + cc),
                         pk, __ATOMIC_RELAXED, __HIP_MEMORY_SCOPE_AGENT);
    }

    // ---- outputs (off the critical path) ---------------------------------
    const int hoff = (b0 + bl) * 1024 + j0 + cc;
    out[(size_t)t * BH + hoff] = h;
    if (t == T_STEPS - 1) {
      out[(size_t)T_STEPS * BH + hoff] = h;       // hT
      out[(size_t)T_STEPS * BH + BH + hoff] = c;  // cT
    } else {
      // ---- xproj for step t+2 (overlaps h-store propagation) -------------
      f32x4 xnew = xv_nxt;
      if (t < T_STEPS - 2) xnew = XPROJ(t & 1);
      xv_cur = xv_nxt;
      xv_nxt = xnew;

      // ---- poll+stage ring slot t+1 into hbf -----------------------------
      STAGE_H((size_t)((t + 1) & (NSLOT - 1)) * BH, (unsigned int)(t + 2));

      // ---- refill x slot (consumed at step t+4-2 = t+2) ------------------
      asm volatile("s_waitcnt lgkmcnt(0)" ::: "memory");
      __builtin_amdgcn_sched_barrier(0);
      if (t < T_STEPS - 4) STAGE_X(t + 4, t & 1);
    }
  }
}

// ---------------------------------------------------------------------------
extern "C" void kernel_launch(void* const* d_in, const int* in_sizes, int n_in,
                              void* d_out, int out_size, void* d_ws, size_t ws_size,
                              hipStream_t stream) {
  const float* x   = (const float*)d_in[0];
  const float* h0  = (const float*)d_in[1];
  const float* c0  = (const float*)d_in[2];
  const float* Wih = (const float*)d_in[3];
  const float* Whh = (const float*)d_in[4];
  const float* bih = (const float*)d_in[5];
  const float* bhh = (const float*)d_in[6];
  float* out = (float*)d_out;
  char* ws = (char*)d_ws;

  unsigned short* xbuf = (unsigned short*)(ws + OFF_XB);
  unsigned int*   ring = (unsigned int*)(ws + OFF_RING);
  unsigned short* wib  = (unsigned short*)(ws + OFF_WIB);
  unsigned short* whb  = (unsigned short*)(ws + OFF_WHB);
  float*          bsum = (float*)(ws + OFF_BSUM);

  hipMemsetAsync(ring, 0, (size_t)NSLOT * BH * sizeof(unsigned int), stream);

  k_cast_bf16<<<dim3(32768), dim3(256), 0, stream>>>(x, xbuf, T_STEPS * BATCH * HID);
  k_cast_bf16<<<dim3(4096),  dim3(256), 0, stream>>>(Wih, wib, G4 * HID);
  k_cast_bf16<<<dim3(4096),  dim3(256), 0, stream>>>(Whh, whb, G4 * HID);
  k_h0_pack<<<dim3(256),     dim3(256), 0, stream>>>(h0, ring);  // slot 0, tag 1
  k_bias<<<dim3(16), dim3(256), 0, stream>>>(bih, bhh, bsum);

  k_lstm<<<dim3(256), dim3(256), 0, stream>>>(whb, wib, xbuf, bsum, c0, ring, out);
}